// Round 10
// baseline (64.335 us; speedup 1.0000x reference)
//
#include <hip/hip_runtime.h>
#include <stdint.h>

#define NUM_LEVELS 21
#define BB 8
#define T 256
#define C 16
#define D 4096
#define NW 128          // 32-d words covering D
#define SROW 9          // u32 per sample row (36 byte-cols, 35 used)

// Full/half adders on 32 bit-lanes (one lane per d)
#define FA(a,b,c,sum,car) { uint32_t t_ = (a)^(b); (sum) = t_^(c); (car) = ((a)&(b)) | (t_&(c)); }
#define HA(a,b,sum,car)   { (sum) = (a)^(b); (car) = (a)&(b); }

// CSA: sum 16 one-bit inputs -> 5 bitplanes (count 0..16 per bit-lane)
__device__ __forceinline__ void csa16(const uint32_t* x, uint32_t* s) {
    uint32_t a0,a1,a2,a3,a4,b0,b1,b2,b3,b4;
    FA(x[0],x[1],x[2],a0,b0); FA(x[3],x[4],x[5],a1,b1); FA(x[6],x[7],x[8],a2,b2);
    FA(x[9],x[10],x[11],a3,b3); FA(x[12],x[13],x[14],a4,b4);
    uint32_t c0,c1,d0,d1,d2;
    FA(a0,a1,a2,c0,d0); FA(a3,a4,x[15],c1,d1);
    HA(c0,c1,s[0],d2);
    uint32_t e0,e1,e2,f0,f1,f2,f3;
    FA(b0,b1,b2,e0,f0); FA(b3,b4,d0,e1,f1);
    FA(e0,e1,d1,e2,f2);
    HA(e2,d2,s[1],f3);
    uint32_t g0,h0,h1;
    FA(f0,f1,f2,g0,h0);
    HA(g0,f3,s[2],h1);
    HA(h0,h1,s[3],s[4]);
}

__global__ __launch_bounds__(256, 4)
void encoder_kernel(const float* __restrict__ x,
                    const float* __restrict__ lw,
                    const float* __restrict__ cw,
                    float* __restrict__ out) {
    __shared__ __align__(16) uint32_t lwTT2[32 * 2];   // [l][wsel] sign words
    __shared__ __align__(16) uint32_t cwTT2[16 * 2];   // [c][wsel]
    __shared__ uint32_t sampC[T * SROW];               // signed m-bytes, 9216 B
    __shared__ int part[8 * 32];

    const int tid = threadIdx.x;
    const int b = blockIdx.x >> 7;
    const int k = blockIdx.x & (NW - 1);   // outputs d = 32k+3 .. 32k+34 (mod D)

    // ---- Phase 0a: quantize own row (t = tid); keep 16 level indices in regs
    int l[16];
    {
        const float* xr = x + (b * T + tid) * C;
        #pragma unroll
        for (int m = 0; m < 4; ++m) {
            float4 v = *(const float4*)(xr + 4 * m);
            float vv[4] = {v.x, v.y, v.z, v.w};
            #pragma unroll
            for (int e = 0; e < 4; ++e) {
                float fi = (vv[e] / 20.0f) * 20.0f;   // exact replica of np ops
                int id = (int)rintf(fi);              // half-to-even == np.round
                id = min(max(id, 0), NUM_LEVELS - 1);
                l[4 * m + e] = id;
            }
        }
    }

    // ---- Phase 0b: bit-transpose weight signs for words k (wsel0), k+1 (wsel1)
    if (tid < 42) {
        const int wsel = tid / 21, lv = tid % 21;
        const float* src = lw + lv * D + 32 * ((k + wsel) & (NW - 1));
        uint32_t w = 0;
        #pragma unroll
        for (int m = 0; m < 8; ++m) {
            float4 v = *(const float4*)(src + 4 * m);
            w |= (__float_as_uint(v.x) >> 31) << (4 * m);
            w |= (__float_as_uint(v.y) >> 31) << (4 * m + 1);
            w |= (__float_as_uint(v.z) >> 31) << (4 * m + 2);
            w |= (__float_as_uint(v.w) >> 31) << (4 * m + 3);
        }
        lwTT2[2 * lv + wsel] = w;
    } else if (tid >= 64 && tid < 96) {
        const int i = tid - 64, wsel = i / 16, c = i % 16;
        const float* src = cw + c * D + 32 * ((k + wsel) & (NW - 1));
        uint32_t w = 0;
        #pragma unroll
        for (int m = 0; m < 8; ++m) {
            float4 v = *(const float4*)(src + 4 * m);
            w |= (__float_as_uint(v.x) >> 31) << (4 * m);
            w |= (__float_as_uint(v.y) >> 31) << (4 * m + 1);
            w |= (__float_as_uint(v.z) >> 31) << (4 * m + 2);
            w |= (__float_as_uint(v.w) >> 31) << (4 * m + 3);
        }
        cwTT2[2 * c + wsel] = w;
    }
    __syncthreads();

    // ---- Phase 1: bit-sliced popcount, then store SIGNED m = 8 - count bytes.
    // SWAR: (0x88 - c) ^ 0x80 == int8(8 - c), no cross-byte borrow since c<=16.
    {
        uint32_t x0[16], x1[16];
        #pragma unroll
        for (int c = 0; c < 16; ++c) {
            uint2 g   = *(const uint2*)&lwTT2[2 * l[c]];   // ds_read_b64 gather
            uint2 cwp = *(const uint2*)&cwTT2[2 * c];      // broadcast
            x0[c] = g.x ^ cwp.x;
            x1[c] = g.y ^ cwp.y;
        }
        uint32_t p0[5], p1[5];
        csa16(x0, p0);
        csa16(x1, p1);
        uint32_t* row = &sampC[tid * SROW];
        #pragma unroll
        for (int g = 0; g < 8; ++g) {
            uint32_t cw32 = 0;
            #pragma unroll
            for (int kk = 0; kk < 5; ++kk) {
                uint32_t nib = (p0[kk] >> (4 * g)) & 0xFu;
                cw32 += ((nib * 0x204081u) & 0x01010101u) << kk;  // byte = count bit kk
            }
            row[g] = (0x88888888u - cw32) ^ 0x80808080u;   // signed bytes 8-c
        }
        {
            uint32_t cw32 = 0;
            #pragma unroll
            for (int kk = 0; kk < 5; ++kk) {
                uint32_t nib = p1[kk] & 0x7u;
                cw32 += ((nib * 0x204081u) & 0x01010101u) << kk;
            }
            row[8] = (0x88888888u - cw32) ^ 0x80808080u;
        }
    }
    __syncthreads();

    // ---- Phase 2: output d=32k+3+j uses cols j..j+3 at rows t..t+3.
    // m-bytes are already signed; sign-extend extract, no subtract.
    // (true sample = 2m; the global 2^4 factor can't change the sign)
    const int j = tid & 31, seg = tid >> 5;
    const int t0 = seg * 32;
    const int rend = min(t0 + 34, 255);
    const int wbase = j >> 2;
    const int sh = (j & 3) * 8;
    int acc = 0;
    int q1 = 0, q2 = 0, q3 = 0;
    const uint32_t* sp = sampC + wbase;
    #pragma unroll
    for (int pr = 0; pr < 3; ++pr) {   // prime pipeline, rows t0..t0+2
        const int r = t0 + pr;
        uint32_t W0 = sp[r * SROW], W1 = sp[r * SROW + 1];
        uint32_t A = (uint32_t)(((((uint64_t)W1) << 32) | W0) >> sh); // bytes j..j+3
        int m0 = (int)(int8_t)(A & 0xFF);
        int m1 = (int)(int8_t)((A >> 8) & 0xFF);
        int m2 = (int)(int8_t)((A >> 16) & 0xFF);
        q3 = __mul24(q2, m2); q2 = __mul24(q1, m1); q1 = m0;
    }
    #pragma unroll 4
    for (int r = t0 + 3; r <= rend; ++r) {
        uint32_t W0 = sp[r * SROW], W1 = sp[r * SROW + 1];
        uint32_t A = (uint32_t)(((((uint64_t)W1) << 32) | W0) >> sh);
        int m0 = (int)(int8_t)(A & 0xFF);
        int m1 = (int)(int8_t)((A >> 8) & 0xFF);
        int m2 = (int)(int8_t)((A >> 16) & 0xFF);
        int m3 = (int)A >> 24;               // arithmetic shift = sign-extended top byte
        acc += __mul24(q3, m3);              // window r-3 completes
        q3 = __mul24(q2, m2); q2 = __mul24(q1, m1); q1 = m0;
    }
    part[seg * 32 + j] = acc;
    __syncthreads();

    // ---- Final reduce + sign
    if (tid < 32) {
        int hv = 0;
        #pragma unroll
        for (int s = 0; s < 8; ++s) hv += part[s * 32 + tid];
        const int d = (32 * k + 3 + tid) & (D - 1);
        out[b * D + d] = hv > 0 ? 1.0f : -1.0f;   // hv==0 -> -1, matches ref
    }
}

extern "C" void kernel_launch(void* const* d_in, const int* in_sizes, int n_in,
                              void* d_out, int out_size, void* d_ws, size_t ws_size,
                              hipStream_t stream) {
    const float* x  = (const float*)d_in[0];
    const float* lw = (const float*)d_in[1];
    const float* cw = (const float*)d_in[2];
    float* out = (float*)d_out;
    encoder_kernel<<<dim3(BB * NW), dim3(256), 0, stream>>>(x, lw, cw, out);
}